// Round 4
// baseline (76.577 us; speedup 1.0000x reference)
//
#include <hip/hip_runtime.h>

typedef _Float16 f16;
typedef f16   f16x4 __attribute__((ext_vector_type(4)));
typedef f16   f16x8 __attribute__((ext_vector_type(8)));
typedef float f32x4 __attribute__((ext_vector_type(4)));

#define K_DIM 512
#define BM 128
#define BN 128
#define BK 32
#define NT (K_DIM / BK)       /* 16 K-steps */
#define N_TILES (K_DIM / BN)  /* 4 */

// direct global->LDS async copy, 16B per lane (dst = wave-uniform base + lane*16)
__device__ __forceinline__ void load_lds16(const void* g, void* l) {
    __builtin_amdgcn_global_load_lds(
        (const __attribute__((address_space(1))) unsigned int*)g,
        (__attribute__((address_space(3))) unsigned int*)l,
        16, 0, 0);
}

// ---------------------------------------------------------------------------
// Weight convert: Wq, Wo (fp32 [512][512]) -> fp16 copies in workspace
// ---------------------------------------------------------------------------
__global__ void convert_w_kernel(const float* __restrict__ wq,
                                 const float* __restrict__ wo,
                                 f16* __restrict__ wq_h,
                                 f16* __restrict__ wo_h) {
    int i = blockIdx.x * blockDim.x + threadIdx.x;
    const int n4 = (512 * 512) / 4;
    const float4* src;
    f16* dst;
    if (i < n4) { src = (const float4*)wq; dst = wq_h; }
    else        { src = (const float4*)wo; dst = wo_h; i -= n4; }
    float4 v = src[i];
    f16* p = dst + (size_t)i * 4;
    p[0] = (f16)v.x; p[1] = (f16)v.y; p[2] = (f16)v.z; p[3] = (f16)v.w;
}

// ---------------------------------------------------------------------------
// GEMM: C[M x 512] = A[M x 512] * B^T   (B stored [N=512][K=512] f16 row-major)
//  CONV_A:  A fp32 -> reg-staged (global f32x4 -> cvt f16 -> ds_write_b128);
//           B via global_load_lds. Loads issued before MFMA, LDS write after
//           (T14 split: A-reg waits at vmcnt(#B-loads), B drains at barrier).
//  else:    A and B both via global_load_lds (f16 source).
// SWAPPED MFMA OPERANDS: acc = mfma(bfr, afr) -> fragment layout
//   m = lane&15, n = (lane>>4)*4 + reg  => thread holds 4 consecutive n.
//  QUANTUM: cumprod(cos()) over 8-wide n-groups = 3 in-reg muls +
//           one shfl_xor(16) (partner holds the other half of the group);
//           f16x4 vector store.  else: f32x4 vector store.
// 256 threads = 4 waves (2x2), wave tile 64x64, mfma_f32_16x16x32_f16
// ---------------------------------------------------------------------------
template <bool CONV_A, bool QUANTUM>
__global__ __launch_bounds__(256, 4)
void gemm_kernel(const void* __restrict__ Aptr,
                 const f16* __restrict__ B,
                 void* __restrict__ Cptr) {
    __shared__ __align__(16) f16 As[2][BM * BK];   // 8KB each buf
    __shared__ __align__(16) f16 Bs[2][BN * BK];   // 8KB each buf

    const int tid  = threadIdx.x;
    const int lane = tid & 63;
    const int wave = tid >> 6;
    const int wm = (wave >> 1) * 64;
    const int wn = (wave & 1) * 64;

    // XCD-chunked bijective swizzle (gridDim.x % 8 == 0), n fastest
    const int bid = blockIdx.x;
    const int chunk = gridDim.x >> 3;
    const int swz = (bid & 7) * chunk + (bid >> 3);
    const int m0 = (swz >> 2) * BM;          // N_TILES == 4
    const int n0 = (swz & 3) * BN;

    const float* Af = (const float*)Aptr;
    const f16*   Ah = (const f16*)Aptr;

    // A reg-staging coords (CONV_A): granules of 8 f32; row = g>>2, col=(g&3)*8
    const int ar = tid >> 2;           // rows ar and ar+64
    const int ac = (tid & 3) * 8;

    float4 sa[4];   // staged A: 2 rows x 8 f32

    auto stage_A_load = [&](int kt) {   // issue global loads (oldest in vmem queue)
        const int k0 = kt * BK;
        const float* p0 = Af + (size_t)(m0 + ar)      * K_DIM + k0 + ac;
        const float* p1 = Af + (size_t)(m0 + ar + 64) * K_DIM + k0 + ac;
        sa[0] = *(const float4*)p0;
        sa[1] = *(const float4*)(p0 + 4);
        sa[2] = *(const float4*)p1;
        sa[3] = *(const float4*)(p1 + 4);
    };
    auto stage_A_write = [&](int buf) { // cvt + LDS write (waits only A's vmcnt)
        f16x8 h0, h1;
#pragma unroll
        for (int r = 0; r < 4; ++r) {
            h0[r]     = (f16)sa[0][r];  h0[4 + r] = (f16)sa[1][r];
            h1[r]     = (f16)sa[2][r];  h1[4 + r] = (f16)sa[3][r];
        }
        *(f16x8*)&As[buf][ar * BK + ac]        = h0;
        *(f16x8*)&As[buf][(ar + 64) * BK + ac] = h1;
    };
    auto stage_A_lds = [&](int buf, int kt) {   // f16 A via global_load_lds
        const int k0 = kt * BK;
#pragma unroll
        for (int c = 0; c < 2; ++c) {
            const int ch = wave * 2 + c;
            const int G = ch * 64 + lane;       // row=G>>2, col=(G&3)*8
            const f16* src = Ah + (size_t)(m0 + (G >> 2)) * K_DIM + k0 + (G & 3) * 8;
            load_lds16(src, (char*)As[buf] + ch * 1024);
        }
    };
    auto stage_B = [&](int buf, int kt) {
        const int k0 = kt * BK;
#pragma unroll
        for (int c = 0; c < 2; ++c) {
            const int ch = wave * 2 + c;
            const int G = ch * 64 + lane;
            const f16* src = B + (size_t)(n0 + (G >> 2)) * K_DIM + k0 + (G & 3) * 8;
            load_lds16(src, (char*)Bs[buf] + ch * 1024);
        }
    };

    f32x4 acc[4][4] = {};

    const int fr = lane & 15;        // fragment index within 16
    const int kq = lane >> 4;        // k-quarter for operands / n-quad for output

    // prologue
    if (CONV_A) { stage_A_load(0); } else { stage_A_lds(0, 0); }
    stage_B(0, 0);
    if (CONV_A) stage_A_write(0);
    __syncthreads();

    for (int t = 0; t < NT; ++t) {
        const int cur = t & 1;
        if (t + 1 < NT) {
            if (CONV_A) stage_A_load(t + 1);      // issue A reg-loads first
            else        stage_A_lds(cur ^ 1, t + 1);
            stage_B(cur ^ 1, t + 1);              // B gload_lds after (newest)
        }

        f16x8 afr[4], bfr[4];
#pragma unroll
        for (int i = 0; i < 4; ++i)
            afr[i] = *(const f16x8*)&As[cur][(wm + i * 16 + fr) * BK + kq * 8];
#pragma unroll
        for (int j = 0; j < 4; ++j)
            bfr[j] = *(const f16x8*)&Bs[cur][(wn + j * 16 + fr) * BK + kq * 8];

        // swapped operands: lane&15 = m, reg = n
#pragma unroll
        for (int i = 0; i < 4; ++i)
#pragma unroll
            for (int j = 0; j < 4; ++j)
                acc[i][j] = __builtin_amdgcn_mfma_f32_16x16x32_f16(bfr[j], afr[i], acc[i][j], 0, 0, 0);

        if (CONV_A && t + 1 < NT) stage_A_write(cur ^ 1);  // A regs ready; B still in flight
        __syncthreads();
    }

    // ---- epilogue ----  m = m0+wm+i*16+fr,  n = n0+wn+j*16+kq*4+r
    if (QUANTUM) {
        f16* Ch = (f16*)Cptr;
#pragma unroll
        for (int i = 0; i < 4; ++i) {
            const int row = m0 + wm + i * 16 + fr;
#pragma unroll
            for (int j = 0; j < 4; ++j) {
                float c0 = __cosf(acc[i][j][0]);
                float c1 = c0 * __cosf(acc[i][j][1]);
                float c2 = c1 * __cosf(acc[i][j][2]);
                float c3 = c2 * __cosf(acc[i][j][3]);
                // partner (lane^16) holds the other half of this 8-group
                float ptot = __shfl_xor(c3, 16, 64);
                float f = (kq & 1) ? ptot : 1.0f;   // odd quad = upper half: prefix it
                f16x4 v = { (f16)(c0 * f), (f16)(c1 * f), (f16)(c2 * f), (f16)(c3 * f) };
                const int col = n0 + wn + j * 16 + kq * 4;
                *(f16x4*)&Ch[(size_t)row * K_DIM + col] = v;
            }
        }
    } else {
        float* Cf = (float*)Cptr;
#pragma unroll
        for (int i = 0; i < 4; ++i) {
            const int row = m0 + wm + i * 16 + fr;
#pragma unroll
            for (int j = 0; j < 4; ++j) {
                const int col = n0 + wn + j * 16 + kq * 4;
                *(f32x4*)&Cf[(size_t)row * K_DIM + col] = acc[i][j];
            }
        }
    }
}

// ---------------------------------------------------------------------------
extern "C" void kernel_launch(void* const* d_in, const int* in_sizes, int n_in,
                              void* d_out, int out_size, void* d_ws, size_t ws_size,
                              hipStream_t stream) {
    const float* x  = (const float*)d_in[0];
    const float* Wq = (const float*)d_in[1];
    // d_in[2]=Wk, d_in[3]=Wv: dead compute in the reference
    const float* Wo = (const float*)d_in[4];

    const int M = in_sizes[0] / K_DIM;   // 32768

    char* ws = (char*)d_ws;
    f16* meas = (f16*)ws;                                    // M*512 f16 (32 MB)
    f16* wq_h = (f16*)(ws + (size_t)M * K_DIM * sizeof(f16));
    f16* wo_h = wq_h + 512 * 512;

    convert_w_kernel<<<512, 256, 0, stream>>>(Wq, Wo, wq_h, wo_h);

    const int nblk = (M / BM) * N_TILES;   // 1024
    gemm_kernel<true, true><<<nblk, 256, 0, stream>>>(x, wq_h, meas);
    gemm_kernel<false, false><<<nblk, 256, 0, stream>>>(meas, wo_h, d_out);
}